// Round 5
// baseline (1451.306 us; speedup 1.0000x reference)
//
#include <hip/hip_runtime.h>
#include <hip/hip_fp16.h>

#define HD 512
#define Bsz 64
#define Tlen 512
#define GB 4
#define RING 16

typedef _Float16 h2v __attribute__((ext_vector_type(2)));
typedef unsigned u32x4 __attribute__((ext_vector_type(4)));
typedef unsigned long long ull;

__device__ __forceinline__ float dot2acc(unsigned a, unsigned b, float c) {
    return __builtin_amdgcn_fdot2(__builtin_bit_cast(h2v, a),
                                  __builtin_bit_cast(h2v, b), c, false);
}

// 16B coherent (MALL) transfers — sc0 sc1, proven pattern.
__device__ __forceinline__ u32x4 mall_ld16(const void* p) {
    u32x4 r;
    asm volatile("global_load_dwordx4 %0, %1, off sc0 sc1\n\ts_waitcnt vmcnt(0)"
                 : "=v"(r) : "v"(p) : "memory");
    return r;
}
__device__ __forceinline__ void mall_st16(void* p, u32x4 v) {
    asm volatile("global_store_dwordx4 %0, %1, off sc0 sc1"
                 :: "v"(p), "v"(v) : "memory");
}
__device__ __forceinline__ unsigned mall_ld4(const unsigned* p) {
    unsigned r;
    asm volatile("global_load_dword %0, %1, off sc0 sc1\n\ts_waitcnt vmcnt(0)"
                 : "=v"(r) : "v"(p) : "memory");
    return r;
}
__device__ __forceinline__ void mall_st4(unsigned* p, unsigned v) {
    asm volatile("global_store_dword %0, %1, off sc0 sc1"
                 :: "v"(p), "v"(v) : "memory");
}

// Non-blocking probe: issue the load, DON'T wait. Resolve later.
__device__ __forceinline__ void probe_ld16(u32x4* d, const void* p) {
    asm volatile("global_load_dwordx4 %0, %1, off sc0 sc1"
                 : "=v"(*d) : "v"(p) : "memory");
}
// Register-tied waitcnt: any use of *d after this sees the landed value.
__device__ __forceinline__ void probe_wait(u32x4* d) {
    asm volatile("s_waitcnt vmcnt(0)" : "+v"(*d) :: "memory");
}

// Sentinel check: ring slots pre-filled with 0xFFFF halves (fp16 -NaN, never
// produced by tanh). A 16B chunk is valid iff no half is 0xFFFF. 16B stores
// are single transactions -> no torn chunks.
__device__ __forceinline__ bool valid8(u32x4 v) {
    unsigned bad = 0;
#pragma unroll
    for (int i = 0; i < 4; ++i) {
        bad |= ((v[i] & 0xFFFFu) == 0xFFFFu);
        bad |= ((v[i] >> 16)     == 0xFFFFu);
    }
    return bad == 0u;
}

// Finish a probed chunk: if the early probe landed valid, zero extra cost;
// otherwise retry-load (one MALL RT per retry) until valid.
__device__ __forceinline__ u32x4 probe_finish(u32x4 v, const void* p) {
    bool ok = valid8(v);
    for (;;) {
        if (!__any((int)(!ok))) break;
        __builtin_amdgcn_s_sleep(1);
        if (!ok) { v = mall_ld16(p); ok = valid8(v); }
    }
    return v;
}

// Fused readiness+data (blocking from the start).
__device__ __forceinline__ u32x4 ring_wait16(const void* p) {
    u32x4 v;
    bool ok = false;
    for (;;) {
        if (!ok) { v = mall_ld16(p); ok = valid8(v); }
        if (!__any((int)(!ok))) break;
        __builtin_amdgcn_s_sleep(1);
    }
    return v;
}

__device__ __forceinline__ void cvt4s(_Float16* d, float4 v) {
    union { ull u; _Float16 h[4]; } t;
    t.h[0] = (_Float16)v.x; t.h[1] = (_Float16)v.y;
    t.h[2] = (_Float16)v.z; t.h[3] = (_Float16)v.w;
    *(ull*)d = t.u;
}

// inb layout: [b2][128 k8-slots][8 halves]  (k8 0-63 = layer input,
// 64-127 = hidden state). Staging lanes (consecutive k8, fixed b2) write
// consecutive 16B chunks -> conflict-free ds_write_b128 (was 2-bank/32-way
// with the old [k8][b2] layout -> 4.19e7 SQ_LDS_BANK_CONFLICT).
__device__ __forceinline__ void gemm4(const u32x4* __restrict__ Ip, const u32x4* wr,
                                      int kq, int kbase, float acc[2][4]) {
#pragma unroll
    for (int i = 0; i < 4; ++i) {
        const int k8 = kbase + kq + 16 * i;
        const u32x4 w0 = wr[i * 2 + 0], w1 = wr[i * 2 + 1];
#pragma unroll
        for (int b = 0; b < 4; ++b) {
            const u32x4 h = Ip[b * 128 + k8];   // 4 distinct addrs/wave: broadcast
#pragma unroll
            for (int e = 0; e < 4; ++e) {
                acc[0][b] = dot2acc(w0[e], h[e], acc[0][b]);
                acc[1][b] = dot2acc(w1[e], h[e], acc[1][b]);
            }
        }
    }
}

// ===========================================================================
// FAST VARIANT: full-length sentinel rings + early-probe pipelining.
// l=0: probe h0_{t-1} BEFORE gemm_ih (hides the MALL RT under compute).
// l=1: block on h0_t (true cross-layer dep), probe h1_{t-1} early and
//      resolve it after gemm_ih (hides that RT under gemm_ih).
// ===========================================================================
__global__ __launch_bounds__(512, 1) void rnn_fullring(
    const float* __restrict__ x, const float* __restrict__ h0in,
    const float* __restrict__ Wih, const float* __restrict__ bih,
    const float* __restrict__ Whh, const float* __restrict__ bhh,
    _Float16* __restrict__ H0r, _Float16* __restrict__ H1r,
    float* __restrict__ out)
{
    __shared__ _Float16 inb[GB * 128 * 8] __attribute__((aligned(16)));
    __shared__ float    part[256 * 17];
    __shared__ _Float16 hout[256] __attribute__((aligned(16)));

    const int bid = blockIdx.x;
    const int g   = bid & 15;
    const int sl  = bid >> 4;
    const int l   = sl >> 3;
    const int rb  = sl & 7;
    const int tid = threadIdx.x;
    const int rh = tid >> 8, kq = (tid >> 4) & 15, rq = tid & 15;

    u32x4 wreg[16];
    {
        const float* WI = Wih + (size_t)l * HD * HD;
        const float* WH = Whh + (size_t)l * HD * HD;
#pragma unroll
        for (int ph = 0; ph < 2; ++ph) {
            const float* W = ph ? WH : WI;
#pragma unroll
            for (int i = 0; i < 4; ++i)
#pragma unroll
                for (int ri = 0; ri < 2; ++ri) {
                    const int row = rb * 64 + rq + 16 * (2 * rh + ri);
                    const float* p = W + (size_t)row * HD + (kq + 16 * i) * 8;
                    union { u32x4 u; _Float16 h[8]; } v;
#pragma unroll
                    for (int e = 0; e < 8; ++e) v.h[e] = (_Float16)p[e];
                    wreg[ph * 8 + i * 2 + ri] = v.u;
                }
        }
    }

    float bias = 0.f;
    if (tid < 256) {
        const int rowg = rb * 64 + (tid & 63);
        bias = bih[l * HD + rowg] + bhh[l * HD + rowg];
    }

    _Float16* ringo = l ? H1r : H0r;
    const u32x4* Ip = (const u32x4*)inb;

    const int bb = tid >> 7;      // l=0 x-staging: batch-in-group
    const int k4 = tid & 127;     // l=0 x-staging: float4 chunk
    const int bglobS = g * GB + bb;
    const int b2 = (tid >> 6) & 3;    // staging: batch
    const int k8 = tid & 63;          // staging: 16B chunk

    float4 xreg;
    if (l == 0) xreg = *(const float4*)(x + (size_t)bglobS * Tlen * HD + k4 * 4);

    for (int t = 0; t < Tlen; ++t) {
        float acc[2][4] = {{0, 0, 0, 0}, {0, 0, 0, 0}};

        if (l == 0) {
            // ---- stage x_t (prefetched reg) ----
            cvt4s(&inb[(bb * 128 + (k4 >> 1)) * 8 + (k4 & 1) * 4], xreg);
            __syncthreads();
            // ---- early probe for h0_{t-1} (or stage h0in at t=0) ----
            const _Float16* hp = H0r + ((size_t)(t - 1) * Bsz + g * GB + b2) * HD + k8 * 8;
            u32x4 pv;
            if (t == 0) {
                if (tid < 256) {
                    const float* src = h0in + (size_t)(g * GB + b2) * HD + k8 * 8;
                    cvt4s(&inb[(b2 * 128 + 64 + k8) * 8],     *(const float4*)src);
                    cvt4s(&inb[(b2 * 128 + 64 + k8) * 8 + 4], *(const float4*)(src + 4));
                }
            } else if (tid < 256) {
                probe_ld16(&pv, hp);          // non-blocking, lands during gemm_ih
            }
            if (t + 1 < Tlen)
                xreg = *(const float4*)(x + ((size_t)bglobS * Tlen + t + 1) * HD + k4 * 4);
            gemm4(Ip, wreg, kq, 0, acc);
            // ---- resolve probe, stage hh input ----
            if (t > 0 && tid < 256) {
                probe_wait(&pv);
                u32x4 v = probe_finish(pv, hp);
                *(u32x4*)&inb[(b2 * 128 + 64 + k8) * 8] = v;
            }
            __syncthreads();
            gemm4(Ip, wreg + 8, kq, 64, acc);
        } else {
            // ---- probe h1_{t-1} early (tid>=256); block on h0_t (tid<256) ----
            const _Float16* hp1 = H1r + ((size_t)(t - 1) * Bsz + g * GB + b2) * HD + k8 * 8;
            u32x4 pv;
            if (tid >= 256) {
                if (t == 0) {
                    const float* src = h0in + (size_t)(Bsz + g * GB + b2) * HD + k8 * 8;
                    cvt4s(&inb[(b2 * 128 + 64 + k8) * 8],     *(const float4*)src);
                    cvt4s(&inb[(b2 * 128 + 64 + k8) * 8 + 4], *(const float4*)(src + 4));
                } else {
                    probe_ld16(&pv, hp1);     // lands during h0-wait + gemm_ih
                }
            } else {
                u32x4 v = ring_wait16(H0r + ((size_t)t * Bsz + g * GB + b2) * HD + k8 * 8);
                *(u32x4*)&inb[(b2 * 128 + k8) * 8] = v;
            }
            __syncthreads();
            gemm4(Ip, wreg, kq, 0, acc);
            if (t > 0 && tid >= 256) {
                probe_wait(&pv);
                u32x4 v = probe_finish(pv, hp1);
                *(u32x4*)&inb[(b2 * 128 + 64 + k8) * 8] = v;
            }
            __syncthreads();
            gemm4(Ip, wreg + 8, kq, 64, acc);
        }

        // ---- reduce across kq, tanh, outputs ----
#pragma unroll
        for (int ri = 0; ri < 2; ++ri)
#pragma unroll
            for (int b = 0; b < 4; ++b)
                part[(size_t)(b * 64 + rq + 16 * (2 * rh + ri)) * 17 + kq] = acc[ri][b];
        __syncthreads();
        if (tid < 256) {
            float s = bias;
#pragma unroll
            for (int k2 = 0; k2 < 16; ++k2) s += part[(size_t)tid * 17 + k2];
            const float hv = tanhf(s);
            hout[tid] = (_Float16)hv;   // |hv|<=1 -> never the 0xFFFF sentinel
            const int rowg = rb * 64 + (tid & 63);
            const int bo = g * GB + (tid >> 6);
            if (l == 1) out[((size_t)bo * Tlen + t) * HD + rowg] = hv;
            if (t == Tlen - 1)
                out[(size_t)Bsz * Tlen * HD + ((size_t)l * Bsz + bo) * HD + rowg] = hv;
        }
        __syncthreads();

        // ---- publish 512B h-slice: fire-and-forget (no drain, no flag) ----
        if (tid < 32) {
            u32x4 v = *(const u32x4*)&hout[(tid >> 3) * 64 + (tid & 7) * 8];
            mall_st16(ringo + ((size_t)t * Bsz + g * GB + (tid >> 3)) * HD + rb * 64 + (tid & 7) * 8, v);
        }
    }
}

// ===========================================================================
// FALLBACK: baseline flag protocol (RING=16), updated only for the new inb
// layout (gemm4 is shared). Selected on the host when ws_size < 64MB.
// ===========================================================================
__device__ __forceinline__ void poll2(unsigned* a, unsigned* b) {
    const int ln = threadIdx.x;  // caller guarantees < 64
    unsigned* fp = nullptr;
    if (ln < 8)       { if (a) fp = a + ln; }
    else if (ln < 16) { if (b) fp = b + (ln - 8); }
    for (;;) {
        unsigned v = fp ? mall_ld4(fp) : 1u;
        if (!__any((int)(v != 1u))) break;
        __builtin_amdgcn_s_sleep(1);
    }
}

__global__ __launch_bounds__(512, 1) void rnn_chain(
    const float* __restrict__ x, const float* __restrict__ h0in,
    const float* __restrict__ Wih, const float* __restrict__ bih,
    const float* __restrict__ Whh, const float* __restrict__ bhh,
    _Float16* __restrict__ H0r, _Float16* __restrict__ H1r,
    unsigned* f0, unsigned* f1, float* __restrict__ out)
{
    __shared__ _Float16 inb[GB * 128 * 8] __attribute__((aligned(16)));
    __shared__ float    part[256 * 17];
    __shared__ _Float16 hout[256] __attribute__((aligned(16)));

    const int bid = blockIdx.x;
    const int g   = bid & 15;
    const int sl  = bid >> 4;
    const int l   = sl >> 3;
    const int rb  = sl & 7;
    const int tid = threadIdx.x;
    const int rh = tid >> 8, kq = (tid >> 4) & 15, rq = tid & 15;

    u32x4 wreg[16];
    {
        const float* WI = Wih + (size_t)l * HD * HD;
        const float* WH = Whh + (size_t)l * HD * HD;
#pragma unroll
        for (int ph = 0; ph < 2; ++ph) {
            const float* W = ph ? WH : WI;
#pragma unroll
            for (int i = 0; i < 4; ++i)
#pragma unroll
                for (int ri = 0; ri < 2; ++ri) {
                    const int row = rb * 64 + rq + 16 * (2 * rh + ri);
                    const float* p = W + (size_t)row * HD + (kq + 16 * i) * 8;
                    union { u32x4 u; _Float16 h[8]; } v;
#pragma unroll
                    for (int e = 0; e < 8; ++e) v.h[e] = (_Float16)p[e];
                    wreg[ph * 8 + i * 2 + ri] = v.u;
                }
        }
    }

    float bias = 0.f;
    if (tid < 256) {
        const int rowg = rb * 64 + (tid & 63);
        bias = bih[l * HD + rowg] + bhh[l * HD + rowg];
    }

    unsigned* fown = (l ? f1 : f0) + ((size_t)g * Tlen) * 8 + rb;
    _Float16* ringo = l ? H1r : H0r;
    const u32x4* Ip = (const u32x4*)inb;

    const int bb = tid >> 7;
    const int k4 = tid & 127;
    const int bglobS = g * GB + bb;

    float4 xreg;
    if (l == 0) xreg = *(const float4*)(x + (size_t)bglobS * Tlen * HD + k4 * 4);

    for (int t = 0; t < Tlen; ++t) {
        const int slot = t & (RING - 1);
        float acc[2][4] = {{0, 0, 0, 0}, {0, 0, 0, 0}};

        if (l == 0) {
            cvt4s(&inb[(bb * 128 + (k4 >> 1)) * 8 + (k4 & 1) * 4], xreg);
            __syncthreads();
            if (t + 1 < Tlen)
                xreg = *(const float4*)(x + ((size_t)bglobS * Tlen + t + 1) * HD + k4 * 4);
            gemm4(Ip, wreg, kq, 0, acc);
            if (tid < 64)
                poll2((t > 0)     ? f0 + ((size_t)g * Tlen + (t - 1)) * 8 : nullptr,
                      (t >= RING) ? f1 + ((size_t)g * Tlen + (t - RING)) * 8 : nullptr);
            __syncthreads();
            if (t == 0) {
                if (tid < 256) {
                    int c2 = tid >> 6, c8 = tid & 63;
                    const float* src = h0in + (size_t)(g * GB + c2) * HD + c8 * 8;
                    cvt4s(&inb[(c2 * 128 + 64 + c8) * 8],     *(const float4*)src);
                    cvt4s(&inb[(c2 * 128 + 64 + c8) * 8 + 4], *(const float4*)(src + 4));
                }
            } else if (tid < 256) {
                int c2 = tid >> 6, c8 = tid & 63;
                u32x4 v = mall_ld16(H0r + ((size_t)((t - 1) & (RING - 1)) * Bsz + g * GB + c2) * HD + c8 * 8);
                *(u32x4*)&inb[(c2 * 128 + 64 + c8) * 8] = v;
            }
            __syncthreads();
            gemm4(Ip, wreg + 8, kq, 64, acc);
        } else {
            if (tid < 64)
                poll2(f0 + ((size_t)g * Tlen + t) * 8,
                      (t > 0) ? f1 + ((size_t)g * Tlen + (t - 1)) * 8 : nullptr);
            __syncthreads();
            if (tid < 256) {
                int c2 = tid >> 6, c8 = tid & 63;
                u32x4 v = mall_ld16(H0r + ((size_t)slot * Bsz + g * GB + c2) * HD + c8 * 8);
                *(u32x4*)&inb[(c2 * 128 + c8) * 8] = v;
            } else if (t == 0) {
                int t2 = tid - 256; int c2 = t2 >> 6, c8 = t2 & 63;
                const float* src = h0in + (size_t)(Bsz + g * GB + c2) * HD + c8 * 8;
                cvt4s(&inb[(c2 * 128 + 64 + c8) * 8],     *(const float4*)src);
                cvt4s(&inb[(c2 * 128 + 64 + c8) * 8 + 4], *(const float4*)(src + 4));
            } else {
                int t2 = tid - 256; int c2 = t2 >> 6, c8 = t2 & 63;
                u32x4 v = mall_ld16(H1r + ((size_t)((t - 1) & (RING - 1)) * Bsz + g * GB + c2) * HD + c8 * 8);
                *(u32x4*)&inb[(c2 * 128 + 64 + c8) * 8] = v;
            }
            __syncthreads();
            gemm4(Ip, wreg, kq, 0, acc);
            gemm4(Ip, wreg + 8, kq, 64, acc);
        }

#pragma unroll
        for (int ri = 0; ri < 2; ++ri)
#pragma unroll
            for (int b = 0; b < 4; ++b)
                part[(size_t)(b * 64 + rq + 16 * (2 * rh + ri)) * 17 + kq] = acc[ri][b];
        __syncthreads();
        if (tid < 256) {
            float s = bias;
#pragma unroll
            for (int k2 = 0; k2 < 16; ++k2) s += part[(size_t)tid * 17 + k2];
            const float hv = tanhf(s);
            hout[tid] = (_Float16)hv;
            const int rowg = rb * 64 + (tid & 63);
            const int bo = g * GB + (tid >> 6);
            if (l == 1) out[((size_t)bo * Tlen + t) * HD + rowg] = hv;
            if (t == Tlen - 1)
                out[(size_t)Bsz * Tlen * HD + ((size_t)l * Bsz + bo) * HD + rowg] = hv;
        }
        __syncthreads();

        if (tid < 32) {
            u32x4 v = *(const u32x4*)&hout[(tid >> 3) * 64 + (tid & 7) * 8];
            mall_st16(ringo + ((size_t)slot * Bsz + g * GB + (tid >> 3)) * HD + rb * 64 + (tid & 7) * 8, v);
        }
        if (tid < 64) {
            asm volatile("s_waitcnt vmcnt(0)" ::: "memory");
            if (tid == 0) mall_st4(fown + (size_t)t * 8, 1u);
        }
    }
}

extern "C" void kernel_launch(void* const* d_in, const int* in_sizes, int n_in,
                              void* d_out, int out_size, void* d_ws, size_t ws_size,
                              hipStream_t stream) {
    const float* x   = (const float*)d_in[0];
    const float* h0  = (const float*)d_in[1];
    const float* Wih = (const float*)d_in[2];
    const float* bih = (const float*)d_in[3];
    const float* Whh = (const float*)d_in[4];
    const float* bhh = (const float*)d_in[5];
    float* out = (float*)d_out;
    char* ws = (char*)d_ws;

    const size_t ring_bytes = (size_t)Tlen * Bsz * HD * sizeof(_Float16);  // 32MB

    if (ws_size >= 2 * ring_bytes) {
        // Fast path: full-length sentinel rings; wiped to 0xFF every launch.
        _Float16* H0r = (_Float16*)ws;
        _Float16* H1r = (_Float16*)(ws + ring_bytes);
        (void)hipMemsetAsync(ws, 0xFF, 2 * ring_bytes, stream);
        void* args[] = { (void*)&x, (void*)&h0, (void*)&Wih, (void*)&bih,
                         (void*)&Whh, (void*)&bhh, (void*)&H0r, (void*)&H1r,
                         (void*)&out };
        (void)hipLaunchCooperativeKernel((const void*)rnn_fullring, dim3(256),
                                         dim3(512), args, 0, stream);
    } else {
        // Fallback: proven baseline protocol.
        unsigned* f0  = (unsigned*)ws;
        unsigned* f1  = (unsigned*)(ws + (256u << 10));
        _Float16* H0r = (_Float16*)(ws + (512u << 10));
        _Float16* H1r = (_Float16*)(ws + (512u << 10) + (1u << 20));
        (void)hipMemsetAsync(ws, 0, 512u << 10, stream);
        void* args[] = { (void*)&x, (void*)&h0, (void*)&Wih, (void*)&bih,
                         (void*)&Whh, (void*)&bhh, (void*)&H0r, (void*)&H1r,
                         (void*)&f0, (void*)&f1, (void*)&out };
        (void)hipLaunchCooperativeKernel((const void*)rnn_chain, dim3(256),
                                         dim3(512), args, 0, stream);
    }
}

// Round 6
// 1257.567 us; speedup vs baseline: 1.1541x; 1.1541x over previous
//
#include <hip/hip_runtime.h>
#include <hip/hip_fp16.h>

#define HD 512
#define Bsz 64
#define Tlen 512
#define GB 4
#define RING 16

typedef _Float16 h2v __attribute__((ext_vector_type(2)));
typedef unsigned u32x4 __attribute__((ext_vector_type(4)));
typedef unsigned long long ull;

__device__ __forceinline__ float dot2acc(unsigned a, unsigned b, float c) {
    return __builtin_amdgcn_fdot2(__builtin_bit_cast(h2v, a),
                                  __builtin_bit_cast(h2v, b), c, false);
}

// 16B coherent (MALL) transfers — sc0 sc1, proven pattern.
__device__ __forceinline__ u32x4 mall_ld16(const void* p) {
    u32x4 r;
    asm volatile("global_load_dwordx4 %0, %1, off sc0 sc1\n\ts_waitcnt vmcnt(0)"
                 : "=v"(r) : "v"(p) : "memory");
    return r;
}
__device__ __forceinline__ void mall_st16(void* p, u32x4 v) {
    asm volatile("global_store_dwordx4 %0, %1, off sc0 sc1"
                 :: "v"(p), "v"(v) : "memory");
}
__device__ __forceinline__ unsigned mall_ld4(const unsigned* p) {
    unsigned r;
    asm volatile("global_load_dword %0, %1, off sc0 sc1\n\ts_waitcnt vmcnt(0)"
                 : "=v"(r) : "v"(p) : "memory");
    return r;
}
__device__ __forceinline__ void mall_st4(unsigned* p, unsigned v) {
    asm volatile("global_store_dword %0, %1, off sc0 sc1"
                 :: "v"(p), "v"(v) : "memory");
}

// Sentinel check: ring slots pre-filled with 0xFFFF halves (fp16 -NaN, never
// produced by tanh). A 16B chunk is valid iff no half is 0xFFFF. 16B stores
// are single transactions -> no torn chunks.
__device__ __forceinline__ bool valid8(u32x4 v) {
    unsigned bad = 0;
#pragma unroll
    for (int i = 0; i < 4; ++i) {
        bad |= ((v[i] & 0xFFFFu) == 0xFFFFu);
        bad |= ((v[i] >> 16)     == 0xFFFFu);
    }
    return bad == 0u;
}

// Fused readiness+data: retry-load until no sentinel. With the ih-prefetch
// schedule the producer published >=1000cy ago -> first load hits.
__device__ __forceinline__ u32x4 ring_wait16(const void* p) {
    u32x4 v;
    bool ok = false;
    for (;;) {
        if (!ok) { v = mall_ld16(p); ok = valid8(v); }
        if (!__any((int)(!ok))) break;
        __builtin_amdgcn_s_sleep(1);
    }
    return v;
}

__device__ __forceinline__ void cvt4s(_Float16* d, float4 v) {
    union { ull u; _Float16 h[4]; } t;
    t.h[0] = (_Float16)v.x; t.h[1] = (_Float16)v.y;
    t.h[2] = (_Float16)v.z; t.h[3] = (_Float16)v.w;
    *(ull*)d = t.u;
}

// inb layout: [b2][128 k8-slots][8 halves]  (k8 0-63 = layer input,
// 64-127 = hidden state). Staging lanes write consecutive 16B chunks ->
// conflict-free ds_write_b128; gemm reads are 4-addr broadcasts.
__device__ __forceinline__ void gemm4(const u32x4* __restrict__ Ip, const u32x4* wr,
                                      int kq, int kbase, float acc[2][4]) {
#pragma unroll
    for (int i = 0; i < 4; ++i) {
        const int k8 = kbase + kq + 16 * i;
        const u32x4 w0 = wr[i * 2 + 0], w1 = wr[i * 2 + 1];
#pragma unroll
        for (int b = 0; b < 4; ++b) {
            const u32x4 h = Ip[b * 128 + k8];
#pragma unroll
            for (int e = 0; e < 4; ++e) {
                acc[0][b] = dot2acc(w0[e], h[e], acc[0][b]);
                acc[1][b] = dot2acc(w1[e], h[e], acc[1][b]);
            }
        }
    }
}

// ===========================================================================
// FAST VARIANT: full-length sentinel rings + one-step ih-GEMM software
// pipeline. Per iteration t:
//   1. stage h_{t-1}     (ring load issued ~1100cy after peers' publish: HIT)
//   2. gemm_hh on top of ih (precomputed last iteration)
//   3. reduce + tanh + out
//   4. publish h_t        (fire-and-forget)
//   5. stage next input   (l0: x_{t+1} local; l1: h0_{t+1} from l0's ring)
//   6. gemm_ih(t+1) -> ih registers   [covers publish->visible latency]
// Accumulation order (ih fully, then hh) identical to baseline -> bit-equal.
// ===========================================================================
__global__ __launch_bounds__(512, 1) void rnn_fullring(
    const float* __restrict__ x, const float* __restrict__ h0in,
    const float* __restrict__ Wih, const float* __restrict__ bih,
    const float* __restrict__ Whh, const float* __restrict__ bhh,
    _Float16* __restrict__ H0r, _Float16* __restrict__ H1r,
    float* __restrict__ out)
{
    __shared__ _Float16 inb[GB * 128 * 8] __attribute__((aligned(16)));
    __shared__ float    part[256 * 17];
    __shared__ _Float16 hout[256] __attribute__((aligned(16)));

    const int bid = blockIdx.x;
    const int g   = bid & 15;
    const int sl  = bid >> 4;
    const int l   = sl >> 3;
    const int rb  = sl & 7;
    const int tid = threadIdx.x;
    const int rh = tid >> 8, kq = (tid >> 4) & 15, rq = tid & 15;

    u32x4 wreg[16];
    {
        const float* WI = Wih + (size_t)l * HD * HD;
        const float* WH = Whh + (size_t)l * HD * HD;
#pragma unroll
        for (int ph = 0; ph < 2; ++ph) {
            const float* W = ph ? WH : WI;
#pragma unroll
            for (int i = 0; i < 4; ++i)
#pragma unroll
                for (int ri = 0; ri < 2; ++ri) {
                    const int row = rb * 64 + rq + 16 * (2 * rh + ri);
                    const float* p = W + (size_t)row * HD + (kq + 16 * i) * 8;
                    union { u32x4 u; _Float16 h[8]; } v;
#pragma unroll
                    for (int e = 0; e < 8; ++e) v.h[e] = (_Float16)p[e];
                    wreg[ph * 8 + i * 2 + ri] = v.u;
                }
        }
    }

    float bias = 0.f;
    if (tid < 256) {
        const int rowg = rb * 64 + (tid & 63);
        bias = bih[l * HD + rowg] + bhh[l * HD + rowg];
    }

    _Float16* ringo = l ? H1r : H0r;
    const u32x4* Ip = (const u32x4*)inb;

    const int bb = tid >> 7;      // l=0 x-staging: batch-in-group
    const int k4 = tid & 127;     // l=0 x-staging: float4 chunk
    const int bglobS = g * GB + bb;
    const int b2 = (tid >> 6) & 3;    // ring staging: batch
    const int k8 = tid & 63;          // ring staging: 16B chunk

    float ih[2][4];
    float4 xreg;

    // ---- prologue: precompute ih for t=0 ----
    if (l == 0) {
        xreg = *(const float4*)(x + (size_t)bglobS * Tlen * HD + k4 * 4);
        cvt4s(&inb[(bb * 128 + (k4 >> 1)) * 8 + (k4 & 1) * 4], xreg);
        __syncthreads();
        xreg = *(const float4*)(x + ((size_t)bglobS * Tlen + 1) * HD + k4 * 4);
    } else {
        if (tid < 256) {
            u32x4 v = ring_wait16(H0r + ((size_t)(g * GB + b2)) * HD + k8 * 8);
            *(u32x4*)&inb[(b2 * 128 + k8) * 8] = v;
        }
        __syncthreads();
    }
#pragma unroll
    for (int ri = 0; ri < 2; ++ri)
#pragma unroll
        for (int b = 0; b < 4; ++b) ih[ri][b] = 0.f;
    gemm4(Ip, wreg, kq, 0, ih);

    for (int t = 0; t < Tlen; ++t) {
        // ---- 1. stage h_{t-1} (same layer) ----
        if (tid < 256) {
            if (t == 0) {
                const float* src = h0in + (size_t)(l * Bsz + g * GB + b2) * HD + k8 * 8;
                cvt4s(&inb[(b2 * 128 + 64 + k8) * 8],     *(const float4*)src);
                cvt4s(&inb[(b2 * 128 + 64 + k8) * 8 + 4], *(const float4*)(src + 4));
            } else {
                u32x4 v = ring_wait16(ringo + ((size_t)(t - 1) * Bsz + g * GB + b2) * HD + k8 * 8);
                *(u32x4*)&inb[(b2 * 128 + 64 + k8) * 8] = v;
            }
        }
        __syncthreads();

        // ---- 2. gemm_hh on top of precomputed ih ----
        float acc[2][4];
#pragma unroll
        for (int ri = 0; ri < 2; ++ri)
#pragma unroll
            for (int b = 0; b < 4; ++b) acc[ri][b] = ih[ri][b];
        gemm4(Ip, wreg + 8, kq, 64, acc);

        // ---- 3. reduce across kq, tanh, outputs ----
#pragma unroll
        for (int ri = 0; ri < 2; ++ri)
#pragma unroll
            for (int b = 0; b < 4; ++b)
                part[(size_t)(b * 64 + rq + 16 * (2 * rh + ri)) * 17 + kq] = acc[ri][b];
        __syncthreads();
        if (tid < 256) {
            float s = bias;
#pragma unroll
            for (int k2 = 0; k2 < 16; ++k2) s += part[(size_t)tid * 17 + k2];
            const float hv = tanhf(s);
            hout[tid] = (_Float16)hv;   // |hv|<=1 -> never the 0xFFFF sentinel
            const int rowg = rb * 64 + (tid & 63);
            const int bo = g * GB + (tid >> 6);
            if (l == 1) out[((size_t)bo * Tlen + t) * HD + rowg] = hv;
            if (t == Tlen - 1)
                out[(size_t)Bsz * Tlen * HD + ((size_t)l * Bsz + bo) * HD + rowg] = hv;
        }
        __syncthreads();

        // ---- 4. publish h_t: fire-and-forget (no drain, no flag) ----
        if (tid < 32) {
            u32x4 v = *(const u32x4*)&hout[(tid >> 3) * 64 + (tid & 7) * 8];
            mall_st16(ringo + ((size_t)t * Bsz + g * GB + (tid >> 3)) * HD + rb * 64 + (tid & 7) * 8, v);
        }

        // ---- 5+6. stage next input, precompute ih(t+1) — covers latency ----
        if (t + 1 < Tlen) {
            if (l == 0) {
                cvt4s(&inb[(bb * 128 + (k4 >> 1)) * 8 + (k4 & 1) * 4], xreg);
                if (t + 2 < Tlen)
                    xreg = *(const float4*)(x + ((size_t)bglobS * Tlen + t + 2) * HD + k4 * 4);
            } else if (tid < 256) {
                u32x4 v = ring_wait16(H0r + ((size_t)(t + 1) * Bsz + g * GB + b2) * HD + k8 * 8);
                *(u32x4*)&inb[(b2 * 128 + k8) * 8] = v;
            }
            __syncthreads();
#pragma unroll
            for (int ri = 0; ri < 2; ++ri)
#pragma unroll
                for (int b = 0; b < 4; ++b) ih[ri][b] = 0.f;
            gemm4(Ip, wreg, kq, 0, ih);
        }
    }
}

// ===========================================================================
// FALLBACK: baseline flag protocol (RING=16). Selected when ws_size < 64MB.
// ===========================================================================
__device__ __forceinline__ void poll2(unsigned* a, unsigned* b) {
    const int ln = threadIdx.x;  // caller guarantees < 64
    unsigned* fp = nullptr;
    if (ln < 8)       { if (a) fp = a + ln; }
    else if (ln < 16) { if (b) fp = b + (ln - 8); }
    for (;;) {
        unsigned v = fp ? mall_ld4(fp) : 1u;
        if (!__any((int)(v != 1u))) break;
        __builtin_amdgcn_s_sleep(1);
    }
}

__global__ __launch_bounds__(512, 1) void rnn_chain(
    const float* __restrict__ x, const float* __restrict__ h0in,
    const float* __restrict__ Wih, const float* __restrict__ bih,
    const float* __restrict__ Whh, const float* __restrict__ bhh,
    _Float16* __restrict__ H0r, _Float16* __restrict__ H1r,
    unsigned* f0, unsigned* f1, float* __restrict__ out)
{
    __shared__ _Float16 inb[GB * 128 * 8] __attribute__((aligned(16)));
    __shared__ float    part[256 * 17];
    __shared__ _Float16 hout[256] __attribute__((aligned(16)));

    const int bid = blockIdx.x;
    const int g   = bid & 15;
    const int sl  = bid >> 4;
    const int l   = sl >> 3;
    const int rb  = sl & 7;
    const int tid = threadIdx.x;
    const int rh = tid >> 8, kq = (tid >> 4) & 15, rq = tid & 15;

    u32x4 wreg[16];
    {
        const float* WI = Wih + (size_t)l * HD * HD;
        const float* WH = Whh + (size_t)l * HD * HD;
#pragma unroll
        for (int ph = 0; ph < 2; ++ph) {
            const float* W = ph ? WH : WI;
#pragma unroll
            for (int i = 0; i < 4; ++i)
#pragma unroll
                for (int ri = 0; ri < 2; ++ri) {
                    const int row = rb * 64 + rq + 16 * (2 * rh + ri);
                    const float* p = W + (size_t)row * HD + (kq + 16 * i) * 8;
                    union { u32x4 u; _Float16 h[8]; } v;
#pragma unroll
                    for (int e = 0; e < 8; ++e) v.h[e] = (_Float16)p[e];
                    wreg[ph * 8 + i * 2 + ri] = v.u;
                }
        }
    }

    float bias = 0.f;
    if (tid < 256) {
        const int rowg = rb * 64 + (tid & 63);
        bias = bih[l * HD + rowg] + bhh[l * HD + rowg];
    }

    unsigned* fown = (l ? f1 : f0) + ((size_t)g * Tlen) * 8 + rb;
    _Float16* ringo = l ? H1r : H0r;
    const u32x4* Ip = (const u32x4*)inb;

    const int bb = tid >> 7;
    const int k4 = tid & 127;
    const int bglobS = g * GB + bb;

    float4 xreg;
    if (l == 0) xreg = *(const float4*)(x + (size_t)bglobS * Tlen * HD + k4 * 4);

    for (int t = 0; t < Tlen; ++t) {
        const int slot = t & (RING - 1);
        float acc[2][4] = {{0, 0, 0, 0}, {0, 0, 0, 0}};

        if (l == 0) {
            cvt4s(&inb[(bb * 128 + (k4 >> 1)) * 8 + (k4 & 1) * 4], xreg);
            __syncthreads();
            if (t + 1 < Tlen)
                xreg = *(const float4*)(x + ((size_t)bglobS * Tlen + t + 1) * HD + k4 * 4);
            gemm4(Ip, wreg, kq, 0, acc);
            if (tid < 64)
                poll2((t > 0)     ? f0 + ((size_t)g * Tlen + (t - 1)) * 8 : nullptr,
                      (t >= RING) ? f1 + ((size_t)g * Tlen + (t - RING)) * 8 : nullptr);
            __syncthreads();
            if (t == 0) {
                if (tid < 256) {
                    int c2 = tid >> 6, c8 = tid & 63;
                    const float* src = h0in + (size_t)(g * GB + c2) * HD + c8 * 8;
                    cvt4s(&inb[(c2 * 128 + 64 + c8) * 8],     *(const float4*)src);
                    cvt4s(&inb[(c2 * 128 + 64 + c8) * 8 + 4], *(const float4*)(src + 4));
                }
            } else if (tid < 256) {
                int c2 = tid >> 6, c8 = tid & 63;
                u32x4 v = mall_ld16(H0r + ((size_t)((t - 1) & (RING - 1)) * Bsz + g * GB + c2) * HD + c8 * 8);
                *(u32x4*)&inb[(c2 * 128 + 64 + c8) * 8] = v;
            }
            __syncthreads();
            gemm4(Ip, wreg + 8, kq, 64, acc);
        } else {
            if (tid < 64)
                poll2(f0 + ((size_t)g * Tlen + t) * 8,
                      (t > 0) ? f1 + ((size_t)g * Tlen + (t - 1)) * 8 : nullptr);
            __syncthreads();
            if (tid < 256) {
                int c2 = tid >> 6, c8 = tid & 63;
                u32x4 v = mall_ld16(H0r + ((size_t)slot * Bsz + g * GB + c2) * HD + c8 * 8);
                *(u32x4*)&inb[(c2 * 128 + c8) * 8] = v;
            } else if (t == 0) {
                int t2 = tid - 256; int c2 = t2 >> 6, c8 = t2 & 63;
                const float* src = h0in + (size_t)(Bsz + g * GB + c2) * HD + c8 * 8;
                cvt4s(&inb[(c2 * 128 + 64 + c8) * 8],     *(const float4*)src);
                cvt4s(&inb[(c2 * 128 + 64 + c8) * 8 + 4], *(const float4*)(src + 4));
            } else {
                int t2 = tid - 256; int c2 = t2 >> 6, c8 = t2 & 63;
                u32x4 v = mall_ld16(H1r + ((size_t)((t - 1) & (RING - 1)) * Bsz + g * GB + c2) * HD + c8 * 8);
                *(u32x4*)&inb[(c2 * 128 + 64 + c8) * 8] = v;
            }
            __syncthreads();
            gemm4(Ip, wreg, kq, 0, acc);
            gemm4(Ip, wreg + 8, kq, 64, acc);
        }

#pragma unroll
        for (int ri = 0; ri < 2; ++ri)
#pragma unroll
            for (int b = 0; b < 4; ++b)
                part[(size_t)(b * 64 + rq + 16 * (2 * rh + ri)) * 17 + kq] = acc[ri][b];
        __syncthreads();
        if (tid < 256) {
            float s = bias;
#pragma unroll
            for (int k2 = 0; k2 < 16; ++k2) s += part[(size_t)tid * 17 + k2];
            const float hv = tanhf(s);
            hout[tid] = (_Float16)hv;
            const int rowg = rb * 64 + (tid & 63);
            const int bo = g * GB + (tid >> 6);
            if (l == 1) out[((size_t)bo * Tlen + t) * HD + rowg] = hv;
            if (t == Tlen - 1)
                out[(size_t)Bsz * Tlen * HD + ((size_t)l * Bsz + bo) * HD + rowg] = hv;
        }
        __syncthreads();

        if (tid < 32) {
            u32x4 v = *(const u32x4*)&hout[(tid >> 3) * 64 + (tid & 7) * 8];
            mall_st16(ringo + ((size_t)slot * Bsz + g * GB + (tid >> 3)) * HD + rb * 64 + (tid & 7) * 8, v);
        }
        if (tid < 64) {
            asm volatile("s_waitcnt vmcnt(0)" ::: "memory");
            if (tid == 0) mall_st4(fown + (size_t)t * 8, 1u);
        }
    }
}

extern "C" void kernel_launch(void* const* d_in, const int* in_sizes, int n_in,
                              void* d_out, int out_size, void* d_ws, size_t ws_size,
                              hipStream_t stream) {
    const float* x   = (const float*)d_in[0];
    const float* h0  = (const float*)d_in[1];
    const float* Wih = (const float*)d_in[2];
    const float* bih = (const float*)d_in[3];
    const float* Whh = (const float*)d_in[4];
    const float* bhh = (const float*)d_in[5];
    float* out = (float*)d_out;
    char* ws = (char*)d_ws;

    const size_t ring_bytes = (size_t)Tlen * Bsz * HD * sizeof(_Float16);  // 32MB

    if (ws_size >= 2 * ring_bytes) {
        // Fast path: full-length sentinel rings; wiped to 0xFF every launch.
        _Float16* H0r = (_Float16*)ws;
        _Float16* H1r = (_Float16*)(ws + ring_bytes);
        (void)hipMemsetAsync(ws, 0xFF, 2 * ring_bytes, stream);
        void* args[] = { (void*)&x, (void*)&h0, (void*)&Wih, (void*)&bih,
                         (void*)&Whh, (void*)&bhh, (void*)&H0r, (void*)&H1r,
                         (void*)&out };
        (void)hipLaunchCooperativeKernel((const void*)rnn_fullring, dim3(256),
                                         dim3(512), args, 0, stream);
    } else {
        // Fallback: proven baseline protocol.
        unsigned* f0  = (unsigned*)ws;
        unsigned* f1  = (unsigned*)(ws + (256u << 10));
        _Float16* H0r = (_Float16*)(ws + (512u << 10));
        _Float16* H1r = (_Float16*)(ws + (512u << 10) + (1u << 20));
        (void)hipMemsetAsync(ws, 0, 512u << 10, stream);
        void* args[] = { (void*)&x, (void*)&h0, (void*)&Wih, (void*)&bih,
                         (void*)&Whh, (void*)&bhh, (void*)&H0r, (void*)&H1r,
                         (void*)&f0, (void*)&f1, (void*)&out };
        (void)hipLaunchCooperativeKernel((const void*)rnn_chain, dim3(256),
                                         dim3(512), args, 0, stream);
    }
}